// Round 1
// baseline (294.578 us; speedup 1.0000x reference)
//
#include <hip/hip_runtime.h>
#include <hip/hip_bf16.h>
#include <math.h>

#define LSEQ 512
#define NA 20
#define NCH 8

// ---------------------------------------------------------------------------
// Kernel A: derive idx (argmax of one-hot, 255 = masked) from x (B, L, A)
// ---------------------------------------------------------------------------
__global__ void idx_kernel(const float* __restrict__ x,
                           unsigned char* __restrict__ g_idx, int total) {
    int i = blockIdx.x * blockDim.x + threadIdx.x;  // position b*L + s
    if (i >= total) return;
    const float* xp = x + (size_t)i * NA;
    int idx = 255;
#pragma unroll
    for (int q = 0; q < 5; ++q) {
        float4 v = ((const float4*)xp)[q];  // 80B per position, 16B aligned
        if (v.x > 0.5f) idx = q * 4 + 0;
        if (v.y > 0.5f) idx = q * 4 + 1;
        if (v.z > 0.5f) idx = q * 4 + 2;
        if (v.w > 0.5f) idx = q * 4 + 3;
    }
    g_idx[i] = (unsigned char)idx;
}

// ---------------------------------------------------------------------------
// Kernel B: VT[r*20+i] = V[i][r], V[i][r] = (r>i && r<=18 ? M[i][r]:0) + (r<i ? M[r][i]:0)
//           M[x][y] = clip(lpm[x][y],0.001,1)*pm[x][y]
// ---------------------------------------------------------------------------
__global__ void vt_kernel(const float* __restrict__ lpm,
                          const float* __restrict__ pm,
                          float* __restrict__ vt) {
    int o = threadIdx.x;
    if (o >= NA * NA) return;
    int r = o / NA, i = o % NA;
    float v = 0.f;
    if (r > i && r <= NA - 2) {
        float l = fminf(fmaxf(lpm[i * NA + r], 0.001f), 1.0f);
        v += l * pm[i * NA + r];
    }
    if (r < i) {
        float l = fminf(fmaxf(lpm[r * NA + i], 0.001f), 1.0f);
        v += l * pm[r * NA + i];
    }
    vt[r * NA + i] = v;
}

// ---------------------------------------------------------------------------
// Kernel C: fused h-build + 9x (conv1d k=3 pad=1 + avgpool2), one wave per (b,a)
// ---------------------------------------------------------------------------
__global__ __launch_bounds__(64) void fused_kernel(
    const unsigned char* __restrict__ g_idx,  // [B*L]
    const float* __restrict__ g_vt,           // [A*A] transposed V
    const float* __restrict__ g_std,          // [1]
    const float* __restrict__ w0,             // [8*3]
    const float* __restrict__ wsg,            // [8*8*8*3]
    float* __restrict__ out)                  // [B*A*CH]
{
    const int a = blockIdx.x;   // 0..19
    const int b = blockIdx.y;   // 0..B-1
    const int t = threadIdx.x;  // 0..63

    __shared__ unsigned char s_idx[LSEQ];
    __shared__ float s_h[LSEQ];
    __shared__ float s_a[NCH * 256];
    __shared__ float s_b[NCH * 128];
    __shared__ float s_v[NA];

    // load idx row (512 B) + V column for this a
    ((uint2*)s_idx)[t] = ((const uint2*)(g_idx + (size_t)b * LSEQ))[t];
    if (t < NA) s_v[t] = g_vt[a * NA + t];
    __syncthreads();

    const float stdv = g_std[0];
    const float inv2s2 = 1.0f / (2.0f * stdv * stdv);
    const float v1 = expf(-1.0f * inv2s2);
    const float v2 = expf(-4.0f * inv2s2);
    const float v3 = expf(-9.0f * inv2s2);

    // ---- build h[s] = xp + column + row ----
    const unsigned char ua = (unsigned char)a;
    for (int s = t; s < LSEQ; s += 64) {
        int ai = s_idx[s];
        float h = 0.f;
        if (ai < NA) h += s_v[ai];
        if (ai == a) h += 1.0f;

        bool mk[4];
#pragma unroll
        for (int k = 1; k <= 3; ++k) {
            bool pos, neg;
            if (s == LSEQ - 1) {
                pos = false;
                for (int u = LSEQ - 1 - k; u <= LSEQ - 1; ++u) pos |= (s_idx[u] == ua);
            } else {
                pos = (s >= k) && (s_idx[s - k] == ua);
            }
            if (s == 0) {
                neg = false;
                for (int u = 0; u <= k; ++u) neg |= (s_idx[u] == ua);
            } else {
                neg = (s + k <= LSEQ - 1) && (s_idx[s + k] == ua);
            }
            mk[k] = pos || neg;
        }
        h += mk[3] ? v3 : (mk[2] ? v2 : (mk[1] ? v1 : 0.f));
        s_h[s] = h;
    }
    __syncthreads();

    const int c = t >> 3;   // output channel 0..7
    const int pb = t & 7;   // position lane 0..7

    // ---- layer 0: 1 -> 8 channels, L=512 -> pooled 256 ----
    {
        float q0 = w0[c * 3 + 0], q1 = w0[c * 3 + 1], q2 = w0[c * 3 + 2];
        float wa = q0, wb = q0 + q1, wc2 = q1 + q2, wd = q2;
        for (int p = pb; p < 256; p += 8) {
            int x = 2 * p;
            float x0 = (x > 0) ? s_h[x - 1] : 0.f;
            float x1 = s_h[x];
            float x2 = s_h[x + 1];
            float x3 = (x + 2 < LSEQ) ? s_h[x + 2] : 0.f;
            s_a[c * 256 + p] = 0.5f * (wa * x0 + wb * x1 + wc2 * x2 + wd * x3);
        }
    }
    __syncthreads();

    // ---- layers 1..8: 8 -> 8 channels, halving each time ----
    int Lin = 256;
    for (int li = 0; li < 8; ++li) {
        const float* fin = (li & 1) ? s_b : s_a;
        float* fout = (li & 1) ? s_a : s_b;
        const int Lout = Lin >> 1;

        float wa[8], wb[8], wc2[8], wd[8];
        const float* wl = wsg + li * 192 + c * 24;
#pragma unroll
        for (int ci = 0; ci < 8; ++ci) {
            float q0 = wl[ci * 3 + 0], q1 = wl[ci * 3 + 1], q2 = wl[ci * 3 + 2];
            wa[ci] = q0; wb[ci] = q0 + q1; wc2[ci] = q1 + q2; wd[ci] = q2;
        }

        for (int p = pb; p < Lout; p += 8) {
            int x = 2 * p;
            float acc = 0.f;
#pragma unroll
            for (int ci = 0; ci < 8; ++ci) {
                const float* ip = fin + ci * Lin + x;
                float x0 = (x > 0) ? ip[-1] : 0.f;
                float x1 = ip[0];
                float x2 = ip[1];
                float x3 = (x + 2 < Lin) ? ip[2] : 0.f;
                acc += wa[ci] * x0 + wb[ci] * x1 + wc2[ci] * x2 + wd[ci] * x3;
            }
            fout[c * Lout + p] = 0.5f * acc;
        }
        __syncthreads();
        Lin = Lout;
    }

    // final result (li=7 wrote s_a, Lout=1): s_a[c]
    if (t < NCH) out[((size_t)b * NA + a) * NCH + t] = s_a[t];
}

extern "C" void kernel_launch(void* const* d_in, const int* in_sizes, int n_in,
                              void* d_out, int out_size, void* d_ws, size_t ws_size,
                              hipStream_t stream) {
    const float* x    = (const float*)d_in[0];
    // d_in[1] = masks (bool) — unused; mask derived from x
    const float* lpm  = (const float*)d_in[2];
    const float* pm   = (const float*)d_in[3];
    const float* stdp = (const float*)d_in[4];
    const float* w0   = (const float*)d_in[5];
    const float* wsg  = (const float*)d_in[6];
    float* out = (float*)d_out;

    const int B = in_sizes[0] / (LSEQ * NA);  // 1024

    float* vt = (float*)d_ws;
    unsigned char* g_idx = (unsigned char*)d_ws + 4096;

    idx_kernel<<<dim3((B * LSEQ + 255) / 256), dim3(256), 0, stream>>>(x, g_idx, B * LSEQ);
    vt_kernel<<<dim3(1), dim3(512), 0, stream>>>(lpm, pm, vt);
    fused_kernel<<<dim3(NA, B), dim3(64), 0, stream>>>(g_idx, vt, stdp, w0, wsg, out);
}

// Round 2
// 130.708 us; speedup vs baseline: 2.2537x; 2.2537x over previous
//
#include <hip/hip_runtime.h>
#include <math.h>

#define LSEQ 512
#define NA 20
#define NCH 8
#define WPAD 516   // padded row length for Wf and h (516%32==4 -> conflict-free strides)

// ---------------------------------------------------------------------------
// vtn[j*20+a] = V[j][a];  V[j][a] = (a>j && a<=18 ? M[j][a]:0) + (a<j ? M[a][j]:0)
// M[x][y] = clip(lpm[x][y],0.001,1)*pm[x][y]
// ---------------------------------------------------------------------------
__global__ void vt_kernel(const float* __restrict__ lpm,
                          const float* __restrict__ pm,
                          float* __restrict__ vtn) {
    int o = threadIdx.x;
    if (o >= NA * NA) return;
    int j = o / NA, a = o % NA;
    float v = 0.f;
    if (a > j && a <= NA - 2)
        v += fminf(fmaxf(lpm[j * NA + a], 0.001f), 1.0f) * pm[j * NA + a];
    if (a < j)
        v += fminf(fmaxf(lpm[a * NA + j], 0.001f), 1.0f) * pm[a * NA + j];
    vtn[o] = v;
}

// ---------------------------------------------------------------------------
// Impulse kernel: Wf[c][s] = pyramid(e_s)[c].  Block per s (re-uses the
// verified R0 pyramid). Blocks s>=512 zero the pad columns.
// ---------------------------------------------------------------------------
__global__ __launch_bounds__(64) void wf_kernel(
    const float* __restrict__ w0,   // [8*3]
    const float* __restrict__ wsg,  // [8*8*8*3]
    float* __restrict__ wf)         // [8*WPAD]
{
    const int s = blockIdx.x;
    const int t = threadIdx.x;
    if (s >= LSEQ) {               // pad columns 512..515 -> 0
        if (t < NCH) wf[t * WPAD + s] = 0.f;
        return;
    }

    __shared__ float s_h[LSEQ];
    __shared__ float s_a[NCH * 256];
    __shared__ float s_b[NCH * 128];

    for (int i = t; i < LSEQ; i += 64) s_h[i] = (i == s) ? 1.f : 0.f;
    __syncthreads();

    const int c = t >> 3;
    const int pb = t & 7;

    // layer 0: 1 -> 8 channels, 512 -> 256
    {
        float q0 = w0[c * 3 + 0], q1 = w0[c * 3 + 1], q2 = w0[c * 3 + 2];
        float wa = q0, wb = q0 + q1, wc2 = q1 + q2, wd = q2;
        for (int p = pb; p < 256; p += 8) {
            int xx = 2 * p;
            float x0 = (xx > 0) ? s_h[xx - 1] : 0.f;
            float x1 = s_h[xx];
            float x2 = s_h[xx + 1];
            float x3 = (xx + 2 < LSEQ) ? s_h[xx + 2] : 0.f;
            s_a[c * 256 + p] = 0.5f * (wa * x0 + wb * x1 + wc2 * x2 + wd * x3);
        }
    }
    __syncthreads();

    int Lin = 256;
    for (int li = 0; li < 8; ++li) {
        const float* fin = (li & 1) ? s_b : s_a;
        float* fout = (li & 1) ? s_a : s_b;
        const int Lout = Lin >> 1;

        float wa[8], wb[8], wc2[8], wd[8];
        const float* wl = wsg + li * 192 + c * 24;
#pragma unroll
        for (int ci = 0; ci < 8; ++ci) {
            float q0 = wl[ci * 3 + 0], q1 = wl[ci * 3 + 1], q2 = wl[ci * 3 + 2];
            wa[ci] = q0; wb[ci] = q0 + q1; wc2[ci] = q1 + q2; wd[ci] = q2;
        }

        for (int p = pb; p < Lout; p += 8) {
            int xx = 2 * p;
            float acc = 0.f;
#pragma unroll
            for (int ci = 0; ci < 8; ++ci) {
                const float* ip = fin + ci * Lin + xx;
                float x0 = (xx > 0) ? ip[-1] : 0.f;
                float x1 = ip[0];
                float x2 = ip[1];
                float x3 = (xx + 2 < Lin) ? ip[2] : 0.f;
                acc += wa[ci] * x0 + wb[ci] * x1 + wc2[ci] * x2 + wd[ci] * x3;
            }
            fout[c * Lout + p] = 0.5f * acc;
        }
        __syncthreads();
        Lin = Lout;
    }

    if (t < NCH) wf[t * WPAD + s] = s_a[t];
}

// ---------------------------------------------------------------------------
// Main kernel: one block per b.  Phases:
//  0: stage x[b] (40KB, coalesced) into LDS (reusing s_h space); load Wf, vtn
//  1: idx[s] = argmax-ish of one-hot (255 = masked)
//  2: build h[a][s] for all 20 a (base column/one-hot + row scatter, k order
//     1,2,3 so larger k wins — matches reference where(mk,vk,row) chain)
//  3: out[b,a,c] = dot(h[a], Wf[c])  (160 threads, conflict-free b128 reads)
// ---------------------------------------------------------------------------
__global__ __launch_bounds__(256) void main_kernel(
    const float* __restrict__ x,      // [B,L,A]
    const float* __restrict__ vtn,    // [20*20]
    const float* __restrict__ g_std,  // [1]
    const float* __restrict__ wf,     // [8*WPAD]
    float* __restrict__ out)          // [B*A*CH]
{
    const int b = blockIdx.x;
    const int t = threadIdx.x;

    __shared__ __align__(16) float s_h[NA * WPAD];    // 41280B; phase0 stages x here (10240 floats)
    __shared__ __align__(16) float s_w[NCH * WPAD];   // 16512B
    __shared__ __align__(16) float s_vtn[NA * NA];
    __shared__ unsigned char s_idx[LSEQ];

    // ---- phase 0: coalesced loads ----
    float4* s_x4 = (float4*)s_h;
    const float4* g_x4 = (const float4*)(x + (size_t)b * LSEQ * NA);
#pragma unroll
    for (int i = t; i < LSEQ * NA / 4; i += 256) s_x4[i] = g_x4[i];

    float4* s_w4 = (float4*)s_w;
    const float4* g_w4 = (const float4*)wf;
    for (int i = t; i < NCH * WPAD / 4; i += 256) s_w4[i] = g_w4[i];

    if (t < NA * NA / 4) ((float4*)s_vtn)[t] = ((const float4*)vtn)[t];
    __syncthreads();

    // ---- phase 1: idx ----
    for (int p = t; p < LSEQ; p += 256) {
        int id = 255;
#pragma unroll
        for (int q = 0; q < 5; ++q) {
            float4 v = s_x4[p * 5 + q];
            if (v.x > .5f) id = 4 * q + 0;
            if (v.y > .5f) id = 4 * q + 1;
            if (v.z > .5f) id = 4 * q + 2;
            if (v.w > .5f) id = 4 * q + 3;
        }
        s_idx[p] = (unsigned char)id;
    }
    __syncthreads();   // idx done; safe to overwrite s_h

    const float stdv = g_std[0];
    const float inv2s2 = 1.f / (2.f * stdv * stdv);
    const float vks[3] = {__expf(-1.f * inv2s2), __expf(-4.f * inv2s2), __expf(-9.f * inv2s2)};

    // ---- phase 2: build h ----
    for (int s = t; s < LSEQ; s += 256) {
        const int ai = s_idx[s];
        const bool valid = ai < NA;
#pragma unroll
        for (int a = 0; a < NA; ++a) {
            float v = valid ? (s_vtn[ai * NA + a] + (a == ai ? 1.f : 0.f)) : 0.f;
            s_h[a * WPAD + s] = v;
        }
#pragma unroll
        for (int k = 1; k <= 3; ++k) {
            const float add = vks[k - 1];
            // pos-shift targets
            if (s == LSEQ - 1) {
                for (int u = LSEQ - 1 - k; u <= LSEQ - 1; ++u) {
                    int tg = s_idx[u];
                    if (tg < NA)
                        s_h[tg * WPAD + s] =
                            (valid ? s_vtn[ai * NA + tg] + (tg == ai ? 1.f : 0.f) : 0.f) + add;
                }
            } else if (s >= k) {
                int tg = s_idx[s - k];
                if (tg < NA)
                    s_h[tg * WPAD + s] =
                        (valid ? s_vtn[ai * NA + tg] + (tg == ai ? 1.f : 0.f) : 0.f) + add;
            }
            // neg-shift targets
            if (s == 0) {
                for (int u = 0; u <= k; ++u) {
                    int tg = s_idx[u];
                    if (tg < NA)
                        s_h[tg * WPAD + s] =
                            (valid ? s_vtn[ai * NA + tg] + (tg == ai ? 1.f : 0.f) : 0.f) + add;
                }
            } else if (s + k < LSEQ) {
                int tg = s_idx[s + k];
                if (tg < NA)
                    s_h[tg * WPAD + s] =
                        (valid ? s_vtn[ai * NA + tg] + (tg == ai ? 1.f : 0.f) : 0.f) + add;
            }
        }
    }
    // zero pad columns 512..515
    if (t < NA * 4) {
        int a = t >> 2, s = LSEQ + (t & 3);
        s_h[a * WPAD + s] = 0.f;
    }
    __syncthreads();

    // ---- phase 3: 160 dot products ----
    if (t < NA * NCH) {
        const int a = t >> 3, c = t & 7;
        const float4* hr = (const float4*)(s_h + a * WPAD);
        const float4* wr = (const float4*)(s_w + c * WPAD);
        float acc = 0.f;
#pragma unroll 3
        for (int j = 0; j < WPAD / 4; ++j) {
            float4 hv = hr[j];
            float4 wv = wr[j];
            acc += hv.x * wv.x + hv.y * wv.y + hv.z * wv.z + hv.w * wv.w;
        }
        out[(size_t)b * (NA * NCH) + t] = acc;
    }
}

extern "C" void kernel_launch(void* const* d_in, const int* in_sizes, int n_in,
                              void* d_out, int out_size, void* d_ws, size_t ws_size,
                              hipStream_t stream) {
    const float* x    = (const float*)d_in[0];
    // d_in[1] = masks (bool) — unused; mask derived from x
    const float* lpm  = (const float*)d_in[2];
    const float* pm   = (const float*)d_in[3];
    const float* stdp = (const float*)d_in[4];
    const float* w0   = (const float*)d_in[5];
    const float* wsg  = (const float*)d_in[6];
    float* out = (float*)d_out;

    const int B = in_sizes[0] / (LSEQ * NA);  // 1024

    float* vtn = (float*)d_ws;                 // 400 floats
    float* wf  = (float*)d_ws + 1024;          // 8*516 floats

    vt_kernel<<<dim3(1), dim3(448), 0, stream>>>(lpm, pm, vtn);
    wf_kernel<<<dim3(WPAD), dim3(64), 0, stream>>>(w0, wsg, wf);
    main_kernel<<<dim3(B), dim3(256), 0, stream>>>(x, vtn, stdp, wf, out);
}